// Round 7
// baseline (18173.676 us; speedup 1.0000x reference)
//
#include <hip/hip_runtime.h>

// ---------------------------------------------------------------------------
// Persistent weight-stationary LSTM, bf16 MFMA, fat-N blocks + 1-hop sync.
// T=1024 B=64 C=256 H=512, 2 layers, fp32 in/out.
//  - 64 blocks x 256 threads (1 block/CU): blocks 0..31 = layer0 (step t),
//    32..63 = layer1 (step t-1). Each block owns 16 h-cols = 64 gate-rows
//    = 4 N-tiles of 16 (was: 128 blocks x 4 cols). Per-block h read volume
//    unchanged -> total LLC h traffic drops 4x: 24 MB/tick -> 6 MB/tick
//    (the R4 bottleneck: full-h bypass reads x 256 blocks congested the LLC).
//  - Waves M-split 64 batches (16 each) as before; per tile the load/MFMA/
//    shuffle/epilogue core is IDENTICAL to R4 with virtual block v=bidL*4+nt.
//    k_wprep reused verbatim (128 virtual blocks).
//  - Weights: streamed per N-tile from XCD-local L2 (96-128 KB/block; all 4
//    waves share -> L1 assists). A-frags (h) forced-live via asm FragLd in
//    ONE LLC round; x packed to bf16 once per tick, reused across tiles.
//  - Barrier: single-hop direct scan. Block b flags slot[b] (monotone tick);
//    every block's wave0 scans all 64 slots (1/lane, ~4K loads/round -- 16x
//    below the R3 meltdown level). No gen hop, no aggregator.
//  - Cross-block data via sc0/sc1 (LLC-coherent); producer order:
//    h-store -> vmcnt(0) -> syncthreads -> flag. out/fin/x-prefetch in the
//    barrier-wait shadow.
//  - mfma_f32_16x16x32_bf16: A[m=lane&15][k=quad*8+j], B(N,K)[n=lane&15][k=quad*8+j],
//    D[m=quad*4+reg][n=lane&15]  (guide-verified mapping, m90/m97 convention)
// ---------------------------------------------------------------------------

#define TT 1024
#define BB 64
#define CC 256
#define HH 512
#define Y_ELEMS (TT * BB * HH)
#define S_ELEMS (BB * HH)

typedef __attribute__((ext_vector_type(8))) short bf16x8;
typedef __attribute__((ext_vector_type(4))) float f32x4;
typedef unsigned int u32;
typedef unsigned short u16;
typedef unsigned long long u64;

// ---- ws layout (bytes) ----
#define WS_BAR 0           // 64 slots * 128B
#define WS_GEN 32768       // (unused, layout stability)
#define WS_BSUM0 36864     // 2048 f32
#define WS_BSUM1 45056     // 2048 f32
#define WS_H0 53248        // 2 * 65536 B (h0 ping-pong, bf16)
#define WS_H1 184320       // 2 * 65536 B
#define WS_WPK0 315392     // 128*24*64*8 bf16  (layer0 packed W, virtual-128)
#define WS_WPK1 3461120    // 128*32*64*8 bf16  (layer1 packed W, virtual-128)
// end 7655424 (~7.66 MB)

__device__ __forceinline__ u16 f2b_rne(float f) {
    u32 u = __float_as_uint(f);
    return (u16)((u + 0x7FFFu + ((u >> 16) & 1u)) >> 16);
}
__device__ __forceinline__ u16 f2b_fast(float f) {  // round-half-up, 2 ops
    return (u16)((__float_as_uint(f) + 0x8000u) >> 16);
}
__device__ __forceinline__ float sigf(float z) { return 1.0f / (1.0f + __expf(-z)); }
__device__ __forceinline__ float tanh_f(float z) { return 2.0f / (1.0f + __expf(-2.0f * z)) - 1.0f; }

__device__ __forceinline__ bf16x8 pack8(float4 a, float4 b) {
    union { u16 u[8]; bf16x8 v; } r;
    r.u[0] = f2b_fast(a.x); r.u[1] = f2b_fast(a.y); r.u[2] = f2b_fast(a.z); r.u[3] = f2b_fast(a.w);
    r.u[4] = f2b_fast(b.x); r.u[5] = f2b_fast(b.y); r.u[6] = f2b_fast(b.z); r.u[7] = f2b_fast(b.w);
    return r.v;
}

__device__ __forceinline__ u32 ld_u32_sc(const u32* p) {
    return __hip_atomic_load(p, __ATOMIC_RELAXED, __HIP_MEMORY_SCOPE_AGENT);
}
__device__ __forceinline__ void st_u32_sc(u32* p, u32 v) {
    __hip_atomic_store(p, v, __ATOMIC_RELAXED, __HIP_MEMORY_SCOPE_AGENT);
}
__device__ __forceinline__ void st_h_sc(u16* p, u16 v) {
    __hip_atomic_store(p, v, __ATOMIC_RELAXED, __HIP_MEMORY_SCOPE_AGENT);
}

// N cache-bypassing 16B loads, base + compile-time offsets (64B stride),
// forced-live destinations -> one LLC latency round.
template <int I, int N>
struct FragLd {
    static __device__ __forceinline__ void go(f32x4* d, const u16* p) {
        asm volatile("global_load_dwordx4 %0, %1, off offset:%c2 sc0 sc1"
                     : "=&v"(d[I]) : "v"(p), "n"(I * 64) : "memory");
        FragLd<I + 1, N>::go(d, p);
    }
};
template <int N>
struct FragLd<N, N> {
    static __device__ __forceinline__ void go(f32x4*, const u16*) {}
};

// ---- init: zero flag region, bsum = bih+bhh, h buffers <- bf16(initial h) ----
__global__ void k_init(const float* __restrict__ bih0, const float* __restrict__ bhh0,
                       const float* __restrict__ bih1, const float* __restrict__ bhh1,
                       const float* __restrict__ h00, const float* __restrict__ h01,
                       unsigned char* __restrict__ ws) {
    u32* bar = (u32*)(ws + WS_BAR);
    float* bs0 = (float*)(ws + WS_BSUM0);
    float* bs1 = (float*)(ws + WS_BSUM1);
    u16* h0 = (u16*)(ws + WS_H0);
    u16* h1 = (u16*)(ws + WS_H1);
    int t = blockIdx.x * 256 + threadIdx.x;  // 32768 threads
    if (t < 8320) bar[t] = 0u;               // slots (+legacy gen) region
    if (t < 2048) { bs0[t] = bih0[t] + bhh0[t]; bs1[t] = bih1[t] + bhh1[t]; }
    if (t < S_ELEMS) { h0[t] = f2b_rne(h00[t]); h1[t] = f2b_rne(h01[t]); }
}

// ---- weight pack (UNCHANGED, 128 virtual blocks of 4 cols each) ----
__global__ void k_wprep(const float* __restrict__ Wih0, const float* __restrict__ Whh0,
                        const float* __restrict__ Wih1, const float* __restrict__ Whh1,
                        unsigned char* __restrict__ ws) {
    u16* wpk0 = (u16*)(ws + WS_WPK0);
    u16* wpk1 = (u16*)(ws + WS_WPK1);
    int u = blockIdx.x * 256 + threadIdx.x;  // 458752 threads
    const float* s;
    u16* d;
    if (u < 128 * 24 * 64) {  // layer0: 8 x-tiles (K=256) + 16 h-tiles (K=512)
        int bidL = u / (24 * 64);
        int kt = (u >> 6) % 24;
        int lane = u & 63;
        int n = lane & 15, quad = lane >> 4;
        int row = (n >> 2) * 512 + bidL * 4 + (n & 3);
        int k = kt * 32 + quad * 8;
        s = (k < 256) ? (Wih0 + (size_t)row * 256 + k) : (Whh0 + (size_t)row * 512 + (k - 256));
        d = wpk0 + (size_t)((bidL * 24 + kt) * 64 + lane) * 8;
    } else {  // layer1: 16 y0-tiles + 16 h1-tiles (K=1024)
        int v = u - 128 * 24 * 64;
        int bidL = v / (32 * 64);
        int kt = (v >> 6) % 32;
        int lane = v & 63;
        int n = lane & 15, quad = lane >> 4;
        int row = (n >> 2) * 512 + bidL * 4 + (n & 3);
        int k = kt * 32 + quad * 8;
        s = (k < 512) ? (Wih1 + (size_t)row * 512 + k) : (Whh1 + (size_t)row * 512 + (k - 512));
        d = wpk1 + (size_t)((bidL * 32 + kt) * 64 + lane) * 8;
    }
    #pragma unroll
    for (int i = 0; i < 8; ++i) d[i] = f2b_rne(s[i]);
}

// ---- the persistent tick loop: bidL in 0..31, 4 N-tiles per block ----
template <int LAYER>
__device__ void run_ticks(const float* __restrict__ x, const float* __restrict__ c0,
                          float* __restrict__ out, unsigned char* __restrict__ ws, int bidL) {
    constexpr int NKT = (LAYER == 0) ? 24 : 32;
    u32* slots = (u32*)(ws + WS_BAR);
    const float* bs = (const float*)(ws + (LAYER == 0 ? WS_BSUM0 : WS_BSUM1));
    u16* h0b[2] = { (u16*)(ws + WS_H0), (u16*)(ws + WS_H0) + S_ELEMS };
    u16* h1b[2] = { (u16*)(ws + WS_H1), (u16*)(ws + WS_H1) + S_ELEMS };
    const u16* wpk = (const u16*)(ws + (LAYER == 0 ? WS_WPK0 : WS_WPK1));

    const int tid = threadIdx.x, lane = tid & 63, wave = tid >> 6;
    const int r16 = lane & 15, quad = lane >> 4, q8 = quad * 8;
    const int gg = r16 >> 2, jj = r16 & 3;
    const int b0 = wave * 16;
    const int myb = b0 + quad * 4 + gg;       // batch this lane finalizes
    const int sl0 = (quad << 4) | (0 << 2) | jj;
    const int sl1 = (quad << 4) | (1 << 2) | jj;
    const int sl2 = (quad << 4) | (2 << 2) | jj;
    const int sl3 = (quad << 4) | (3 << 2) | jj;

    // per-tile columns & biases (hoisted); c state in registers all run
    int colv[4];
    float bi4[4], bf4[4], bg4[4], bo4[4], c4[4];
    #pragma unroll
    for (int nt = 0; nt < 4; ++nt) {
        colv[nt] = (bidL * 4 + nt) * 4 + jj;
        bi4[nt] = bs[0 * HH + colv[nt]];
        bf4[nt] = bs[1 * HH + colv[nt]];
        bg4[nt] = bs[2 * HH + colv[nt]];
        bo4[nt] = bs[3 * HH + colv[nt]];
        c4[nt] = c0[myb * HH + colv[nt]];
    }

    // layer0: x prefetch registers (t=0 issued before the loop)
    float4 xf0[8], xf1[8];
    if (LAYER == 0) {
        const float* xp = x + (size_t)(b0 + r16) * CC + q8;
        #pragma unroll
        for (int kt = 0; kt < 8; ++kt) {
            xf0[kt] = *(const float4*)(xp + kt * 32);
            xf1[kt] = *(const float4*)(xp + kt * 32 + 4);
        }
    }

    for (int i = 0; i <= TT; ++i) {
        const bool active = (LAYER == 0) ? (i < TT) : (i >= 1);
        const int t = (LAYER == 0) ? i : i - 1;
        float h4[4] = {0.f, 0.f, 0.f, 0.f};
        if (active) {
            // ---- A-fragment loads: one LLC round (asm, forced-live) ----
            f32x4 afr[LAYER == 0 ? 16 : 32];
            if (LAYER == 0) {
                const u16* hp = h0b[t & 1] + (size_t)(b0 + r16) * HH + q8;
                FragLd<0, 16>::go(afr, hp);
            } else {
                const u16* pa = h0b[(t + 1) & 3 & 1] + (size_t)(b0 + r16) * HH + q8; // y0[t]
                const u16* pb = h1b[t & 1] + (size_t)(b0 + r16) * HH + q8;           // h1[t-1]
                FragLd<0, 16>::go(afr + 16, pb);
                FragLd<0, 16>::go(afr, pa);
            }
            // layer0: pack x once per tick, reused across the 4 N-tiles
            bf16x8 xb[8];
            if (LAYER == 0) {
                #pragma unroll
                for (int kt = 0; kt < 8; ++kt) xb[kt] = pack8(xf0[kt], xf1[kt]);
            }
            bool waited = false;
            #pragma unroll
            for (int nt = 0; nt < 4; ++nt) {
                const int v = bidL * 4 + nt;
                // W tile: streamed (cached) from L1/L2; waves share the tile
                const u16* wp = wpk + (size_t)(v * NKT) * 512 + (size_t)lane * 8;
                f32x4 wt[NKT];
                #pragma unroll
                for (int kt = 0; kt < NKT; ++kt) wt[kt] = *(const f32x4*)(wp + (size_t)kt * 512);
                f32x4 a0 = {0.f,0.f,0.f,0.f}, a1 = {0.f,0.f,0.f,0.f};
                f32x4 a2 = {0.f,0.f,0.f,0.f}, a3 = {0.f,0.f,0.f,0.f};
                if (LAYER == 0) {
                    #pragma unroll
                    for (int kt = 0; kt < 8; ++kt) {   // x proj overlaps h-load flight (nt=0)
                        bf16x8 wv = __builtin_bit_cast(bf16x8, wt[kt]);
                        f32x4& dst = (kt & 2) ? ((kt & 1) ? a3 : a2) : ((kt & 1) ? a1 : a0);
                        dst = __builtin_amdgcn_mfma_f32_16x16x32_bf16(xb[kt], wv, dst, 0, 0, 0);
                    }
                    if (!waited) {   // afr written by asm: compiler can't track -> explicit
                        asm volatile("s_waitcnt vmcnt(0)" ::: "memory");
                        __builtin_amdgcn_sched_barrier(0);
                        waited = true;
                    }
                    #pragma unroll
                    for (int kt = 0; kt < 16; ++kt) {
                        bf16x8 av = __builtin_bit_cast(bf16x8, afr[kt]);
                        bf16x8 wv = __builtin_bit_cast(bf16x8, wt[8 + kt]);
                        f32x4& dst = (kt & 2) ? ((kt & 1) ? a3 : a2) : ((kt & 1) ? a1 : a0);
                        dst = __builtin_amdgcn_mfma_f32_16x16x32_bf16(av, wv, dst, 0, 0, 0);
                    }
                } else {
                    if (!waited) {
                        asm volatile("s_waitcnt vmcnt(0)" ::: "memory");
                        __builtin_amdgcn_sched_barrier(0);
                        waited = true;
                    }
                    #pragma unroll
                    for (int kt = 0; kt < 32; ++kt) {
                        bf16x8 av = __builtin_bit_cast(bf16x8, afr[kt]);
                        bf16x8 wv = __builtin_bit_cast(bf16x8, wt[kt]);
                        f32x4& dst = (kt & 2) ? ((kt & 1) ? a3 : a2) : ((kt & 1) ? a1 : a0);
                        dst = __builtin_amdgcn_mfma_f32_16x16x32_bf16(av, wv, dst, 0, 0, 0);
                    }
                }
                f32x4 acc = (a0 + a1) + (a2 + a3);

                // gates for (myb, colv[nt])
                float gi = 0.f, gf = 0.f, gc = 0.f, go = 0.f;
                #pragma unroll
                for (int r = 0; r < 4; ++r) {
                    float v0 = __shfl(acc[r], sl0, 64);
                    float v1 = __shfl(acc[r], sl1, 64);
                    float v2 = __shfl(acc[r], sl2, 64);
                    float v3 = __shfl(acc[r], sl3, 64);
                    if (r == gg) { gi = v0; gf = v1; gc = v2; go = v3; }
                }
                gi = sigf(gi + bi4[nt]);
                gf = sigf(gf + bf4[nt]);
                gc = tanh_f(gc + bg4[nt]);
                go = sigf(go + bo4[nt]);
                c4[nt] = gf * c4[nt] + gi * gc;
                const float h = go * tanh_f(c4[nt]);
                h4[nt] = h;

                u16* hw = (LAYER == 0) ? h0b[(t + 1) & 1] : h1b[(t + 1) & 1];
                st_h_sc(&hw[myb * HH + colv[nt]], f2b_rne(h));
            }
        }
        // ---- barrier arrival: drain h stores, then raise flag ----
        if (i < TT) {
            asm volatile("s_waitcnt vmcnt(0)" ::: "memory");
            __syncthreads();   // all waves of this block drained
            if (tid == 0)
                st_u32_sc(&slots[(u32)blockIdx.x * 32], (u32)(i + 1));
        }
        // ---- shadow work while flags propagate / peers finish ----
        if (active) {
            if (LAYER == 1) {
                #pragma unroll
                for (int nt = 0; nt < 4; ++nt)
                    out[(size_t)t * S_ELEMS + myb * HH + colv[nt]] = h4[nt];
            }
            if (t == TT - 1) {
                float* fin = out + Y_ELEMS + (LAYER == 0 ? 0 : 2) * S_ELEMS;
                #pragma unroll
                for (int nt = 0; nt < 4; ++nt) {
                    fin[myb * HH + colv[nt]] = h4[nt];
                    fin[S_ELEMS + myb * HH + colv[nt]] = c4[nt];
                }
            }
        }
        if (LAYER == 0 && i + 1 < TT) {      // prefetch x[t+1] into registers
            const float* xp = x + ((size_t)(i + 1) * BB + b0 + r16) * CC + q8;
            #pragma unroll
            for (int kt = 0; kt < 8; ++kt) {
                xf0[kt] = *(const float4*)(xp + kt * 32);
                xf1[kt] = *(const float4*)(xp + kt * 32 + 4);
            }
        }
        // ---- barrier completion: direct scan, wave0 = 1 slot per lane ----
        if (i < TT) {
            const u32 tgt = (u32)(i + 1);
            if (tid < 64) {
                const u32* sp = slots + (u32)tid * 32;
                while (true) {
                    u32 vls = ld_u32_sc(sp);
                    if (__all((int)(vls >= tgt))) break;
                }
            }
            __syncthreads();
        }
    }
}

__global__ __launch_bounds__(256) __attribute__((amdgpu_waves_per_eu(1, 1)))
void k_lstm(const float* __restrict__ x,
            const float* __restrict__ c00,
            const float* __restrict__ c01,
            float* __restrict__ out,
            unsigned char* __restrict__ ws) {
    const int bid = blockIdx.x;
    if (bid < 32) run_ticks<0>(x, c00, out, ws, bid);
    else          run_ticks<1>(x, c01, out, ws, bid - 32);
}

extern "C" void kernel_launch(void* const* d_in, const int* in_sizes, int n_in,
                              void* d_out, int out_size, void* d_ws, size_t ws_size,
                              hipStream_t stream) {
    const float* x    = (const float*)d_in[0];
    const float* h0_0 = (const float*)d_in[1];
    const float* c0_0 = (const float*)d_in[2];
    const float* h0_1 = (const float*)d_in[3];
    const float* c0_1 = (const float*)d_in[4];
    const float* Wih0 = (const float*)d_in[5];
    const float* Whh0 = (const float*)d_in[6];
    const float* bih0 = (const float*)d_in[7];
    const float* bhh0 = (const float*)d_in[8];
    const float* Wih1 = (const float*)d_in[9];
    const float* Whh1 = (const float*)d_in[10];
    const float* bih1 = (const float*)d_in[11];
    const float* bhh1 = (const float*)d_in[12];
    float* out = (float*)d_out;
    unsigned char* ws = (unsigned char*)d_ws;

    k_init<<<128, 256, 0, stream>>>(bih0, bhh0, bih1, bhh1, h0_0, h0_1, ws);
    k_wprep<<<1792, 256, 0, stream>>>(Wih0, Whh0, Wih1, Whh1, ws);
    k_lstm<<<64, 256, 0, stream>>>(x, c0_0, c0_1, out, ws);
}

// Round 8
// 9432.539 us; speedup vs baseline: 1.9267x; 1.9267x over previous
//
#include <hip/hip_runtime.h>

// ---------------------------------------------------------------------------
// Persistent LSTM, bf16 MFMA, fat-N blocks + W-in-LDS + 1-hop sync.
// T=1024 B=64 C=256 H=512, 2 layers, fp32 in/out.
//  - 64 blocks x 256 threads (1 block/CU): blocks 0..31 = layer0 (step t),
//    32..63 = layer1 (step t-1). Each block owns 16 h-cols = 4 N-tiles.
//    Total LLC h-broadcast traffic: 24 MB/tick (R4) -> 6 MB/tick.
//  - R7 failed on registers (afr[32]+wt[32] = 256 VGPR -> scratch spills).
//    FIX: packed W lives in LDS (96/128 KB, staged once). MFMA loop reads
//    W in chunks of 8 x ds_read_b128 (lane-contiguous, conflict-free),
//    pipelined by the compiler against MFMAs. afr stays in VGPRs.
//  - h-fragment loads: asm global_load_dwordx4 sc0 sc1, forced-live, one
//    LLC round; vmcnt(0) + sched_barrier before consuming MFMAs.
//  - Barrier: single-hop. Block b flags slot[b] (monotone tick); every
//    block's wave0 scans all 64 slots (1/lane, ~4K loads/round). No gen hop.
//  - Producer order: 4x h-store -> vmcnt(0) -> syncthreads -> flag.
//    out/fin stores + x[t+1] prefetch in the barrier-wait shadow.
//  - mfma_f32_16x16x32_bf16: A[m=lane&15][k=quad*8+j], B(N,K)[n=lane&15][k=quad*8+j],
//    D[m=quad*4+reg][n=lane&15]  (guide-verified mapping, m90/m97 convention)
// ---------------------------------------------------------------------------

#define TT 1024
#define BB 64
#define CC 256
#define HH 512
#define Y_ELEMS (TT * BB * HH)
#define S_ELEMS (BB * HH)

typedef __attribute__((ext_vector_type(8))) short bf16x8;
typedef __attribute__((ext_vector_type(4))) float f32x4;
typedef unsigned int u32;
typedef unsigned short u16;
typedef unsigned long long u64;

// ---- ws layout (bytes) ----
#define WS_BAR 0           // 64 slots * 128B
#define WS_GEN 32768       // (unused, layout stability)
#define WS_BSUM0 36864     // 2048 f32
#define WS_BSUM1 45056     // 2048 f32
#define WS_H0 53248        // 2 * 65536 B (h0 ping-pong, bf16)
#define WS_H1 184320       // 2 * 65536 B
#define WS_WPK0 315392     // 128*24*64*8 bf16  (layer0 packed W, virtual-128)
#define WS_WPK1 3461120    // 128*32*64*8 bf16  (layer1 packed W, virtual-128)
// end 7655424 (~7.66 MB)

#define SMEM_BYTES 131072  // 4 tiles * 32 kt * 1KB (layer1 worst case)

__device__ __forceinline__ u16 f2b_rne(float f) {
    u32 u = __float_as_uint(f);
    return (u16)((u + 0x7FFFu + ((u >> 16) & 1u)) >> 16);
}
__device__ __forceinline__ u16 f2b_fast(float f) {  // round-half-up, 2 ops
    return (u16)((__float_as_uint(f) + 0x8000u) >> 16);
}
__device__ __forceinline__ float sigf(float z) { return 1.0f / (1.0f + __expf(-z)); }
__device__ __forceinline__ float tanh_f(float z) { return 2.0f / (1.0f + __expf(-2.0f * z)) - 1.0f; }

__device__ __forceinline__ bf16x8 pack8(float4 a, float4 b) {
    union { u16 u[8]; bf16x8 v; } r;
    r.u[0] = f2b_fast(a.x); r.u[1] = f2b_fast(a.y); r.u[2] = f2b_fast(a.z); r.u[3] = f2b_fast(a.w);
    r.u[4] = f2b_fast(b.x); r.u[5] = f2b_fast(b.y); r.u[6] = f2b_fast(b.z); r.u[7] = f2b_fast(b.w);
    return r.v;
}

__device__ __forceinline__ u32 ld_u32_sc(const u32* p) {
    return __hip_atomic_load(p, __ATOMIC_RELAXED, __HIP_MEMORY_SCOPE_AGENT);
}
__device__ __forceinline__ void st_u32_sc(u32* p, u32 v) {
    __hip_atomic_store(p, v, __ATOMIC_RELAXED, __HIP_MEMORY_SCOPE_AGENT);
}
__device__ __forceinline__ void st_h_sc(u16* p, u16 v) {
    __hip_atomic_store(p, v, __ATOMIC_RELAXED, __HIP_MEMORY_SCOPE_AGENT);
}

// N cache-bypassing 16B loads, base + compile-time offsets (64B stride),
// forced-live destinations -> one LLC latency round.
template <int I, int N>
struct FragLd {
    static __device__ __forceinline__ void go(f32x4* d, const u16* p) {
        asm volatile("global_load_dwordx4 %0, %1, off offset:%c2 sc0 sc1"
                     : "=&v"(d[I]) : "v"(p), "n"(I * 64) : "memory");
        FragLd<I + 1, N>::go(d, p);
    }
};
template <int N>
struct FragLd<N, N> {
    static __device__ __forceinline__ void go(f32x4*, const u16*) {}
};

// ---- init: zero flag region, bsum = bih+bhh, h buffers <- bf16(initial h) ----
__global__ void k_init(const float* __restrict__ bih0, const float* __restrict__ bhh0,
                       const float* __restrict__ bih1, const float* __restrict__ bhh1,
                       const float* __restrict__ h00, const float* __restrict__ h01,
                       unsigned char* __restrict__ ws) {
    u32* bar = (u32*)(ws + WS_BAR);
    float* bs0 = (float*)(ws + WS_BSUM0);
    float* bs1 = (float*)(ws + WS_BSUM1);
    u16* h0 = (u16*)(ws + WS_H0);
    u16* h1 = (u16*)(ws + WS_H1);
    int t = blockIdx.x * 256 + threadIdx.x;  // 32768 threads
    if (t < 8320) bar[t] = 0u;               // slots (+legacy gen) region
    if (t < 2048) { bs0[t] = bih0[t] + bhh0[t]; bs1[t] = bih1[t] + bhh1[t]; }
    if (t < S_ELEMS) { h0[t] = f2b_rne(h00[t]); h1[t] = f2b_rne(h01[t]); }
}

// ---- weight pack (UNCHANGED, 128 virtual blocks of 4 cols each) ----
__global__ void k_wprep(const float* __restrict__ Wih0, const float* __restrict__ Whh0,
                        const float* __restrict__ Wih1, const float* __restrict__ Whh1,
                        unsigned char* __restrict__ ws) {
    u16* wpk0 = (u16*)(ws + WS_WPK0);
    u16* wpk1 = (u16*)(ws + WS_WPK1);
    int u = blockIdx.x * 256 + threadIdx.x;  // 458752 threads
    const float* s;
    u16* d;
    if (u < 128 * 24 * 64) {  // layer0: 8 x-tiles (K=256) + 16 h-tiles (K=512)
        int bidL = u / (24 * 64);
        int kt = (u >> 6) % 24;
        int lane = u & 63;
        int n = lane & 15, quad = lane >> 4;
        int row = (n >> 2) * 512 + bidL * 4 + (n & 3);
        int k = kt * 32 + quad * 8;
        s = (k < 256) ? (Wih0 + (size_t)row * 256 + k) : (Whh0 + (size_t)row * 512 + (k - 256));
        d = wpk0 + (size_t)((bidL * 24 + kt) * 64 + lane) * 8;
    } else {  // layer1: 16 y0-tiles + 16 h1-tiles (K=1024)
        int v = u - 128 * 24 * 64;
        int bidL = v / (32 * 64);
        int kt = (v >> 6) % 32;
        int lane = v & 63;
        int n = lane & 15, quad = lane >> 4;
        int row = (n >> 2) * 512 + bidL * 4 + (n & 3);
        int k = kt * 32 + quad * 8;
        s = (k < 512) ? (Wih1 + (size_t)row * 512 + k) : (Whh1 + (size_t)row * 512 + (k - 512));
        d = wpk1 + (size_t)((bidL * 32 + kt) * 64 + lane) * 8;
    }
    #pragma unroll
    for (int i = 0; i < 8; ++i) d[i] = f2b_rne(s[i]);
}

// ---- the persistent tick loop: bidL in 0..31, 4 N-tiles per block ----
template <int LAYER>
__device__ void run_ticks(const float* __restrict__ x, const float* __restrict__ c0,
                          float* __restrict__ out, unsigned char* __restrict__ ws, int bidL) {
    constexpr int NKT = (LAYER == 0) ? 24 : 32;
    extern __shared__ __align__(16) u16 smem[];   // [nt][kt][lane][8] bf16
    u32* slots = (u32*)(ws + WS_BAR);
    const float* bs = (const float*)(ws + (LAYER == 0 ? WS_BSUM0 : WS_BSUM1));
    u16* h0b[2] = { (u16*)(ws + WS_H0), (u16*)(ws + WS_H0) + S_ELEMS };
    u16* h1b[2] = { (u16*)(ws + WS_H1), (u16*)(ws + WS_H1) + S_ELEMS };
    const u16* wpk = (const u16*)(ws + (LAYER == 0 ? WS_WPK0 : WS_WPK1));

    const int tid = threadIdx.x, lane = tid & 63, wave = tid >> 6;
    const int r16 = lane & 15, quad = lane >> 4, q8 = quad * 8;
    const int gg = r16 >> 2, jj = r16 & 3;
    const int b0 = wave * 16;
    const int myb = b0 + quad * 4 + gg;       // batch this lane finalizes
    const int sl0 = (quad << 4) | (0 << 2) | jj;
    const int sl1 = (quad << 4) | (1 << 2) | jj;
    const int sl2 = (quad << 4) | (2 << 2) | jj;
    const int sl3 = (quad << 4) | (3 << 2) | jj;

    // ---- stage this block's 4 W tiles into LDS (once) ----
    {
        const u16* src = wpk + (size_t)(bidL * 4 * NKT) * 512;  // 4 contiguous tiles
        for (int ofs = tid * 8; ofs < 4 * NKT * 512; ofs += 256 * 8)
            *(f32x4*)(smem + ofs) = *(const f32x4*)(src + ofs);
        __syncthreads();
    }

    // per-tile columns & biases (hoisted); c state in registers all run
    int colv[4];
    float bi4[4], bf4[4], bg4[4], bo4[4], c4[4];
    #pragma unroll
    for (int nt = 0; nt < 4; ++nt) {
        colv[nt] = (bidL * 4 + nt) * 4 + jj;
        bi4[nt] = bs[0 * HH + colv[nt]];
        bf4[nt] = bs[1 * HH + colv[nt]];
        bg4[nt] = bs[2 * HH + colv[nt]];
        bo4[nt] = bs[3 * HH + colv[nt]];
        c4[nt] = c0[myb * HH + colv[nt]];
    }

    // layer0: x prefetch registers (t=0 issued before the loop)
    float4 xf0[8], xf1[8];
    if (LAYER == 0) {
        const float* xp = x + (size_t)(b0 + r16) * CC + q8;
        #pragma unroll
        for (int kt = 0; kt < 8; ++kt) {
            xf0[kt] = *(const float4*)(xp + kt * 32);
            xf1[kt] = *(const float4*)(xp + kt * 32 + 4);
        }
    }

    for (int i = 0; i <= TT; ++i) {
        const bool active = (LAYER == 0) ? (i < TT) : (i >= 1);
        const int t = (LAYER == 0) ? i : i - 1;
        float h4[4] = {0.f, 0.f, 0.f, 0.f};
        if (active) {
            // ---- A-fragment loads: one LLC round (asm, forced-live) ----
            f32x4 afr[LAYER == 0 ? 16 : 32];
            if (LAYER == 0) {
                const u16* hp = h0b[t & 1] + (size_t)(b0 + r16) * HH + q8;
                FragLd<0, 16>::go(afr, hp);
            } else {
                const u16* pa = h0b[(t + 1) & 1] + (size_t)(b0 + r16) * HH + q8; // y0[t]
                const u16* pb = h1b[t & 1] + (size_t)(b0 + r16) * HH + q8;       // h1[t-1]
                FragLd<0, 16>::go(afr + 16, pb);
                FragLd<0, 16>::go(afr, pa);
            }
            bool waited = false;
            #pragma unroll
            for (int nt = 0; nt < 4; ++nt) {
                const u16* wbase = smem + (size_t)(nt * NKT) * 512 + (size_t)lane * 8;
                f32x4 a0 = {0.f,0.f,0.f,0.f}, a1 = {0.f,0.f,0.f,0.f};
                f32x4 a2 = {0.f,0.f,0.f,0.f}, a3 = {0.f,0.f,0.f,0.f};
                if (LAYER == 0) {
                    // x projection (registers + LDS W) — overlaps h-load flight at nt=0
                    #pragma unroll
                    for (int kt = 0; kt < 8; ++kt) {
                        bf16x8 a = pack8(xf0[kt], xf1[kt]);
                        bf16x8 wv = *(const bf16x8*)(wbase + (size_t)kt * 512);
                        f32x4& dst = (kt & 2) ? ((kt & 1) ? a3 : a2) : ((kt & 1) ? a1 : a0);
                        dst = __builtin_amdgcn_mfma_f32_16x16x32_bf16(a, wv, dst, 0, 0, 0);
                    }
                    if (!waited) {   // afr written by asm -> explicit wait
                        asm volatile("s_waitcnt vmcnt(0)" ::: "memory");
                        __builtin_amdgcn_sched_barrier(0);
                        waited = true;
                    }
                    #pragma unroll
                    for (int kc = 8; kc < 24; kc += 8) {
                        f32x4 wt[8];
                        #pragma unroll
                        for (int j = 0; j < 8; ++j) wt[j] = *(const f32x4*)(wbase + (size_t)(kc + j) * 512);
                        #pragma unroll
                        for (int j = 0; j < 8; ++j) {
                            const int kt = kc - 8 + j;
                            bf16x8 av = __builtin_bit_cast(bf16x8, afr[kt]);
                            bf16x8 wv = __builtin_bit_cast(bf16x8, wt[j]);
                            f32x4& dst = (kt & 2) ? ((kt & 1) ? a3 : a2) : ((kt & 1) ? a1 : a0);
                            dst = __builtin_amdgcn_mfma_f32_16x16x32_bf16(av, wv, dst, 0, 0, 0);
                        }
                    }
                } else {
                    if (!waited) {
                        asm volatile("s_waitcnt vmcnt(0)" ::: "memory");
                        __builtin_amdgcn_sched_barrier(0);
                        waited = true;
                    }
                    #pragma unroll
                    for (int kc = 0; kc < 32; kc += 8) {
                        f32x4 wt[8];
                        #pragma unroll
                        for (int j = 0; j < 8; ++j) wt[j] = *(const f32x4*)(wbase + (size_t)(kc + j) * 512);
                        #pragma unroll
                        for (int j = 0; j < 8; ++j) {
                            const int kt = kc + j;
                            bf16x8 av = __builtin_bit_cast(bf16x8, afr[kt]);
                            bf16x8 wv = __builtin_bit_cast(bf16x8, wt[j]);
                            f32x4& dst = (kt & 2) ? ((kt & 1) ? a3 : a2) : ((kt & 1) ? a1 : a0);
                            dst = __builtin_amdgcn_mfma_f32_16x16x32_bf16(av, wv, dst, 0, 0, 0);
                        }
                    }
                }
                f32x4 acc = (a0 + a1) + (a2 + a3);

                // gates for (myb, colv[nt])
                float gi = 0.f, gf = 0.f, gc = 0.f, go = 0.f;
                #pragma unroll
                for (int r = 0; r < 4; ++r) {
                    float v0 = __shfl(acc[r], sl0, 64);
                    float v1 = __shfl(acc[r], sl1, 64);
                    float v2 = __shfl(acc[r], sl2, 64);
                    float v3 = __shfl(acc[r], sl3, 64);
                    if (r == gg) { gi = v0; gf = v1; gc = v2; go = v3; }
                }
                gi = sigf(gi + bi4[nt]);
                gf = sigf(gf + bf4[nt]);
                gc = tanh_f(gc + bg4[nt]);
                go = sigf(go + bo4[nt]);
                c4[nt] = gf * c4[nt] + gi * gc;
                const float h = go * tanh_f(c4[nt]);
                h4[nt] = h;

                u16* hw = (LAYER == 0) ? h0b[(t + 1) & 1] : h1b[(t + 1) & 1];
                st_h_sc(&hw[myb * HH + colv[nt]], f2b_rne(h));
            }
        }
        // ---- barrier arrival: drain h stores, then raise flag ----
        if (i < TT) {
            asm volatile("s_waitcnt vmcnt(0)" ::: "memory");
            __syncthreads();   // all waves of this block drained
            if (tid == 0)
                st_u32_sc(&slots[(u32)blockIdx.x * 32], (u32)(i + 1));
        }
        // ---- shadow work while flags propagate / peers finish ----
        if (active) {
            if (LAYER == 1) {
                #pragma unroll
                for (int nt = 0; nt < 4; ++nt)
                    out[(size_t)t * S_ELEMS + myb * HH + colv[nt]] = h4[nt];
            }
            if (t == TT - 1) {
                float* fin = out + Y_ELEMS + (LAYER == 0 ? 0 : 2) * S_ELEMS;
                #pragma unroll
                for (int nt = 0; nt < 4; ++nt) {
                    fin[myb * HH + colv[nt]] = h4[nt];
                    fin[S_ELEMS + myb * HH + colv[nt]] = c4[nt];
                }
            }
        }
        if (LAYER == 0 && i + 1 < TT) {      // prefetch x[t+1] into registers
            const float* xp = x + ((size_t)(i + 1) * BB + b0 + r16) * CC + q8;
            #pragma unroll
            for (int kt = 0; kt < 8; ++kt) {
                xf0[kt] = *(const float4*)(xp + kt * 32);
                xf1[kt] = *(const float4*)(xp + kt * 32 + 4);
            }
        }
        // ---- barrier completion: direct scan, wave0 = 1 slot per lane ----
        if (i < TT) {
            const u32 tgt = (u32)(i + 1);
            if (tid < 64) {
                const u32* sp = slots + (u32)tid * 32;
                while (true) {
                    u32 vls = ld_u32_sc(sp);
                    if (__all((int)(vls >= tgt))) break;
                }
            }
            __syncthreads();
        }
    }
}

__global__ __launch_bounds__(256) __attribute__((amdgpu_waves_per_eu(1, 1)))
void k_lstm(const float* __restrict__ x,
            const float* __restrict__ c00,
            const float* __restrict__ c01,
            float* __restrict__ out,
            unsigned char* __restrict__ ws) {
    const int bid = blockIdx.x;
    if (bid < 32) run_ticks<0>(x, c00, out, ws, bid);
    else          run_ticks<1>(x, c01, out, ws, bid - 32);
}

extern "C" void kernel_launch(void* const* d_in, const int* in_sizes, int n_in,
                              void* d_out, int out_size, void* d_ws, size_t ws_size,
                              hipStream_t stream) {
    const float* x    = (const float*)d_in[0];
    const float* h0_0 = (const float*)d_in[1];
    const float* c0_0 = (const float*)d_in[2];
    const float* h0_1 = (const float*)d_in[3];
    const float* c0_1 = (const float*)d_in[4];
    const float* Wih0 = (const float*)d_in[5];
    const float* Whh0 = (const float*)d_in[6];
    const float* bih0 = (const float*)d_in[7];
    const float* bhh0 = (const float*)d_in[8];
    const float* Wih1 = (const float*)d_in[9];
    const float* Whh1 = (const float*)d_in[10];
    const float* bih1 = (const float*)d_in[11];
    const float* bhh1 = (const float*)d_in[12];
    float* out = (float*)d_out;
    unsigned char* ws = (unsigned char*)d_ws;

    static bool smem_set = false;
    if (!smem_set) {
        (void)hipFuncSetAttribute((const void*)k_lstm,
                                  hipFuncAttributeMaxDynamicSharedMemorySize, SMEM_BYTES);
        smem_set = true;
    }

    k_init<<<128, 256, 0, stream>>>(bih0, bhh0, bih1, bhh1, h0_0, h0_1, ws);
    k_wprep<<<1792, 256, 0, stream>>>(Wih0, Whh0, Wih1, Whh1, ws);
    k_lstm<<<64, 256, SMEM_BYTES, stream>>>(x, c0_0, c0_1, out, ws);
}

// Round 9
// 6498.419 us; speedup vs baseline: 2.7966x; 1.4515x over previous
//
#include <hip/hip_runtime.h>

// ---------------------------------------------------------------------------
// Persistent weight-stationary LSTM, bf16 MFMA, R4 structure + L2-served h.
// T=1024 B=64 C=256 H=512, 2 layers, fp32 in/out.
//  - 256 blocks x 256 threads, 1 block/CU; blocks 0..127 = layer0 (step t),
//    128..255 = layer1 (step t-1); R4's flag barrier (block flags -> block0
//    wave-scan -> gen lines -> tid0 poll) -- unchanged.
//  - NEW: h state is an 8-deep ring; consumer h loads are sc0-ONLY (bypass
//    L1, ALLOCATE in XCD L2). 32 blocks/XCD share one MSHR-merged LLC pull
//    -> LLC h traffic 24 MB/tick -> ~1-2 MB/tick (R4's congestion term).
//  - Staleness: producers still write h sc0+sc1 (write-through to LLC), so
//    LLC is always fresh; a per-XCD leader (elected via s_getreg XCC_ID +
//    atomicAdd -- hardware truth, not dispatch mapping) invalidates its L2
//    every 4 ticks (fence acquire/agent => buffer_inv sc1). Ring reuse
//    distance 8 > read-window 2 + inv period 4 => no stale read possible.
//    Invalidate at any time is correctness-neutral (LLC fresh).
//  - If ws_size < ring requirement: byte-identical R4 fallback (2-slot ring,
//    sc0sc1 bypass loads, no inv) -- never regress.
//  - mfma_f32_16x16x32_bf16: A[m=lane&15][k=quad*8+j], B(N,K)[n=lane&15][k=quad*8+j],
//    D[m=quad*4+reg][n=lane&15]  (guide-verified mapping, m90/m97 convention)
// ---------------------------------------------------------------------------

#define TT 1024
#define BB 64
#define CC 256
#define HH 512
#define Y_ELEMS (TT * BB * HH)
#define S_ELEMS (BB * HH)

typedef __attribute__((ext_vector_type(8))) short bf16x8;
typedef __attribute__((ext_vector_type(4))) float f32x4;
typedef unsigned int u32;
typedef unsigned short u16;
typedef unsigned long long u64;

// ---- ws layout (bytes) ----
#define WS_BAR 0            // 256 slots * 128B
#define WS_GEN 32768        // 4 gen lines * 128B (ends 33280)
#define WS_XCD 33280        // 8 u32 election counters
#define WS_BSUM0 36864      // 2048 f32
#define WS_BSUM1 45056      // 2048 f32
#define WS_WPK0 53248       // 128*24*64*8 bf16 (3,145,728 B)
#define WS_WPK1 3198976     // 128*32*64*8 bf16 (4,194,304 B)
#define WS_H0   7393280     // h0 ring slots (65536 B each)
#define H_SLOT_BYTES 65536
// cached mode: 8 slots/layer -> end = 7393280 + 16*65536 = 8,441,856

__device__ __forceinline__ u16 f2b_rne(float f) {
    u32 u = __float_as_uint(f);
    return (u16)((u + 0x7FFFu + ((u >> 16) & 1u)) >> 16);
}
__device__ __forceinline__ u16 f2b_fast(float f) {  // round-half-up, 2 ops
    return (u16)((__float_as_uint(f) + 0x8000u) >> 16);
}
__device__ __forceinline__ float sigf(float z) { return 1.0f / (1.0f + __expf(-z)); }
__device__ __forceinline__ float tanh_f(float z) { return 2.0f / (1.0f + __expf(-2.0f * z)) - 1.0f; }

__device__ __forceinline__ bf16x8 pack8(float4 a, float4 b) {
    union { u16 u[8]; bf16x8 v; } r;
    r.u[0] = f2b_fast(a.x); r.u[1] = f2b_fast(a.y); r.u[2] = f2b_fast(a.z); r.u[3] = f2b_fast(a.w);
    r.u[4] = f2b_fast(b.x); r.u[5] = f2b_fast(b.y); r.u[6] = f2b_fast(b.z); r.u[7] = f2b_fast(b.w);
    return r.v;
}

__device__ __forceinline__ u32 ld_u32_sc(const u32* p) {
    return __hip_atomic_load(p, __ATOMIC_RELAXED, __HIP_MEMORY_SCOPE_AGENT);
}
__device__ __forceinline__ void st_u32_sc(u32* p, u32 v) {
    __hip_atomic_store(p, v, __ATOMIC_RELAXED, __HIP_MEMORY_SCOPE_AGENT);
}
__device__ __forceinline__ void st_h_sc(u16* p, u16 v) {
    __hip_atomic_store(p, v, __ATOMIC_RELAXED, __HIP_MEMORY_SCOPE_AGENT);
}

// N 16B loads, base + compile-time offsets, back-to-back, forced-live
// destinations -> one latency round.
// CACHED: sc0 only (bypass L1, allocate in XCD L2 -> shared among 32 blocks).
// !CACHED: sc0 sc1 (LLC-coherent bypass) -- the R4 path.
template <int I, int N, bool CACHED>
struct FragLd {
    static __device__ __forceinline__ void go(f32x4* d, const u16* p) {
        if constexpr (CACHED)
            asm volatile("global_load_dwordx4 %0, %1, off offset:%c2 sc0"
                         : "=&v"(d[I]) : "v"(p), "n"(I * 64) : "memory");
        else
            asm volatile("global_load_dwordx4 %0, %1, off offset:%c2 sc0 sc1"
                         : "=&v"(d[I]) : "v"(p), "n"(I * 64) : "memory");
        FragLd<I + 1, N, CACHED>::go(d, p);
    }
};
template <int N, bool CACHED>
struct FragLd<N, N, CACHED> {
    static __device__ __forceinline__ void go(f32x4*, const u16*) {}
};

// ---- init: zero flags/counters, bsum = bih+bhh, h slot0 <- bf16(initial h) ----
__global__ void k_init(const float* __restrict__ bih0, const float* __restrict__ bhh0,
                       const float* __restrict__ bih1, const float* __restrict__ bhh1,
                       const float* __restrict__ h00, const float* __restrict__ h01,
                       unsigned char* __restrict__ ws, u64 h1off) {
    u32* bar = (u32*)(ws + WS_BAR);
    float* bs0 = (float*)(ws + WS_BSUM0);
    float* bs1 = (float*)(ws + WS_BSUM1);
    u16* h0 = (u16*)(ws + WS_H0);
    u16* h1 = (u16*)(ws + h1off);
    int t = blockIdx.x * 256 + threadIdx.x;  // 32768 threads
    if (t < 8448) bar[t] = 0u;               // slots + gen + xcd counters
    if (t < 2048) { bs0[t] = bih0[t] + bhh0[t]; bs1[t] = bih1[t] + bhh1[t]; }
    if (t < S_ELEMS) { h0[t] = f2b_rne(h00[t]); h1[t] = f2b_rne(h01[t]); }
}

// ---- weight pack: fp32 [4H,K] -> bf16 B-frag order wpk[bidL][kt][lane][8] ----
// rows permuted: n-index (lane&15) = gg*4+jj  <->  W row = gg*512 + bidL*4 + jj
__global__ void k_wprep(const float* __restrict__ Wih0, const float* __restrict__ Whh0,
                        const float* __restrict__ Wih1, const float* __restrict__ Whh1,
                        unsigned char* __restrict__ ws) {
    u16* wpk0 = (u16*)(ws + WS_WPK0);
    u16* wpk1 = (u16*)(ws + WS_WPK1);
    int u = blockIdx.x * 256 + threadIdx.x;  // 458752 threads
    const float* s;
    u16* d;
    if (u < 128 * 24 * 64) {  // layer0: 8 x-tiles (K=256) + 16 h-tiles (K=512)
        int bidL = u / (24 * 64);
        int kt = (u >> 6) % 24;
        int lane = u & 63;
        int n = lane & 15, quad = lane >> 4;
        int row = (n >> 2) * 512 + bidL * 4 + (n & 3);
        int k = kt * 32 + quad * 8;
        s = (k < 256) ? (Wih0 + (size_t)row * 256 + k) : (Whh0 + (size_t)row * 512 + (k - 256));
        d = wpk0 + (size_t)((bidL * 24 + kt) * 64 + lane) * 8;
    } else {  // layer1: 16 y0-tiles + 16 h1-tiles (K=1024)
        int v = u - 128 * 24 * 64;
        int bidL = v / (32 * 64);
        int kt = (v >> 6) % 32;
        int lane = v & 63;
        int n = lane & 15, quad = lane >> 4;
        int row = (n >> 2) * 512 + bidL * 4 + (n & 3);
        int k = kt * 32 + quad * 8;
        s = (k < 512) ? (Wih1 + (size_t)row * 512 + k) : (Whh1 + (size_t)row * 512 + (k - 512));
        d = wpk1 + (size_t)((bidL * 32 + kt) * 64 + lane) * 8;
    }
    #pragma unroll
    for (int i = 0; i < 8; ++i) d[i] = f2b_rne(s[i]);
}

// ---- the persistent tick loop, templated on layer & h-transport mode ----
template <int LAYER, bool CACHED>
__device__ void run_ticks(const float* __restrict__ x, const float* __restrict__ c0,
                          float* __restrict__ out, unsigned char* __restrict__ ws,
                          int bidL, u32 rmask, u64 h1off) {
    constexpr int NKT = (LAYER == 0) ? 24 : 32;
    u32* slots = (u32*)(ws + WS_BAR);
    u32* gen = (u32*)(ws + WS_GEN);
    const float* bs = (const float*)(ws + (LAYER == 0 ? WS_BSUM0 : WS_BSUM1));
    u16* h0base = (u16*)(ws + WS_H0);
    u16* h1base = (u16*)(ws + h1off);
    const u16* wpk = (const u16*)(ws + (LAYER == 0 ? WS_WPK0 : WS_WPK1));

    const int tid = threadIdx.x, lane = tid & 63, wave = tid >> 6;
    const int r16 = lane & 15, quad = lane >> 4, q8 = quad * 8;
    const int gg = r16 >> 2, jj = r16 & 3;
    const int b0 = wave * 16;
    const int col = bidL * 4 + jj;            // h column this lane finalizes
    const int myb = b0 + quad * 4 + gg;       // batch this lane finalizes
    const int sl0 = (quad << 4) | (0 << 2) | jj;
    const int sl1 = (quad << 4) | (1 << 2) | jj;
    const int sl2 = (quad << 4) | (2 << 2) | jj;
    const int sl3 = (quad << 4) | (3 << 2) | jj;

    // per-XCD leader election (hardware XCC id, not dispatch mapping)
    u32 isLeader = 0;
    if (CACHED && tid == 0) {
        u32 xcd;
        asm volatile("s_getreg_b32 %0, hwreg(HW_REG_XCC_ID)" : "=s"(xcd));
        u32* cnt = (u32*)(ws + WS_XCD) + (xcd & 7u);
        isLeader = (__hip_atomic_fetch_add(cnt, 1u, __ATOMIC_RELAXED,
                                           __HIP_MEMORY_SCOPE_AGENT) == 0u);
    }

    // biases (hoisted), c state in register for the whole run
    const float bi = bs[0 * HH + col], bf_ = bs[1 * HH + col];
    const float bg = bs[2 * HH + col], bo = bs[3 * HH + col];
    float c = c0[myb * HH + col];

    // weight fragments: load once; reloads (if rematerialized) hit L1/L2
    f32x4 wf[NKT];
    {
        const u16* wp = wpk + (size_t)(bidL * NKT * 64 + lane) * 8;
        #pragma unroll
        for (int kt = 0; kt < NKT; ++kt) wf[kt] = *(const f32x4*)(wp + (size_t)kt * 64 * 8);
        #pragma unroll
        for (int kt = 0; kt < NKT; ++kt) asm volatile("" : "+v"(wf[kt]));
    }

    // layer0: x prefetch registers (t=0 issued before the loop)
    float4 xf0[8], xf1[8];
    if (LAYER == 0) {
        const float* xp = x + (size_t)(b0 + r16) * CC + q8;
        #pragma unroll
        for (int kt = 0; kt < 8; ++kt) {
            xf0[kt] = *(const float4*)(xp + kt * 32);
            xf1[kt] = *(const float4*)(xp + kt * 32 + 4);
        }
    }

    for (int i = 0; i <= TT; ++i) {
        const bool active = (LAYER == 0) ? (i < TT) : (i >= 1);
        const int t = (LAYER == 0) ? i : i - 1;
        float h = 0.f;
        if (active) {
            f32x4 a0 = {0.f,0.f,0.f,0.f}, a1 = {0.f,0.f,0.f,0.f};
            f32x4 a2 = {0.f,0.f,0.f,0.f}, a3 = {0.f,0.f,0.f,0.f};
            if (LAYER == 0) {
                // 16 recurrent h fragments (slot t): one latency round
                f32x4 afr[16];
                const u16* hp = h0base + (size_t)((u32)t & rmask) * S_ELEMS
                              + (size_t)(b0 + r16) * HH + q8;
                FragLd<0, 16, CACHED>::go(afr, hp);
                // x projection from prefetched registers overlaps the h-load flight
                #pragma unroll
                for (int kt = 0; kt < 8; ++kt) {
                    bf16x8 a = pack8(xf0[kt], xf1[kt]);
                    bf16x8 wv = __builtin_bit_cast(bf16x8, wf[kt]);
                    f32x4& dst = (kt & 2) ? ((kt & 1) ? a3 : a2) : ((kt & 1) ? a1 : a0);
                    dst = __builtin_amdgcn_mfma_f32_16x16x32_bf16(a, wv, dst, 0, 0, 0);
                }
                asm volatile("s_waitcnt vmcnt(0)" ::: "memory");
                __builtin_amdgcn_sched_barrier(0);
                #pragma unroll
                for (int kt = 0; kt < 16; ++kt) {
                    bf16x8 av = __builtin_bit_cast(bf16x8, afr[kt]);
                    bf16x8 wv = __builtin_bit_cast(bf16x8, wf[8 + kt]);
                    f32x4& dst = (kt & 2) ? ((kt & 1) ? a3 : a2) : ((kt & 1) ? a1 : a0);
                    dst = __builtin_amdgcn_mfma_f32_16x16x32_bf16(av, wv, dst, 0, 0, 0);
                }
            } else {
                // y0[t] = h0 slot t+1 (layer0 wrote at its tick t); h1 = slot t
                f32x4 afr[32];
                const u16* pa = h0base + (size_t)((u32)(t + 1) & rmask) * S_ELEMS
                              + (size_t)(b0 + r16) * HH + q8;
                const u16* pb = h1base + (size_t)((u32)t & rmask) * S_ELEMS
                              + (size_t)(b0 + r16) * HH + q8;
                FragLd<0, 16, CACHED>::go(afr + 16, pb);
                FragLd<0, 16, CACHED>::go(afr, pa);
                asm volatile("s_waitcnt vmcnt(0)" ::: "memory");
                __builtin_amdgcn_sched_barrier(0);
                #pragma unroll
                for (int kt = 0; kt < 32; ++kt) {
                    bf16x8 av = __builtin_bit_cast(bf16x8, afr[kt]);
                    bf16x8 wv = __builtin_bit_cast(bf16x8, wf[kt]);
                    f32x4& dst = (kt & 2) ? ((kt & 1) ? a3 : a2) : ((kt & 1) ? a1 : a0);
                    dst = __builtin_amdgcn_mfma_f32_16x16x32_bf16(av, wv, dst, 0, 0, 0);
                }
            }
            f32x4 acc = (a0 + a1) + (a2 + a3);

            // gates for (myb, col): lanes sharing (quad,jj), gg = gate
            float gi = 0.f, gf = 0.f, gc = 0.f, go = 0.f;
            #pragma unroll
            for (int r = 0; r < 4; ++r) {
                float v0 = __shfl(acc[r], sl0, 64);
                float v1 = __shfl(acc[r], sl1, 64);
                float v2 = __shfl(acc[r], sl2, 64);
                float v3 = __shfl(acc[r], sl3, 64);
                if (r == gg) { gi = v0; gf = v1; gc = v2; go = v3; }
            }
            gi = sigf(gi + bi);
            gf = sigf(gf + bf_);
            gc = tanh_f(gc + bg);
            go = sigf(go + bo);
            c = gf * c + gi * gc;
            h = go * tanh_f(c);

            // h store: slot t+1, write-through to LLC (the only pre-flag store)
            u16* hw = (LAYER == 0) ? (h0base + (size_t)((u32)(t + 1) & rmask) * S_ELEMS)
                                   : (h1base + (size_t)((u32)(t + 1) & rmask) * S_ELEMS);
            st_h_sc(&hw[myb * HH + col], f2b_rne(h));
        }
        // ---- barrier arrival: drain h store, then raise flag ----
        if (i < TT) {
            asm volatile("s_waitcnt vmcnt(0)" ::: "memory");
            __syncthreads();   // all waves of this block drained
            if (tid == 0) {
                st_u32_sc(&slots[(u32)blockIdx.x * 32], (u32)(i + 1));
                // per-XCD L2 invalidate every 4 ticks (leader only).
                // LLC always fresh -> correctness-neutral, kills stale copies
                // well before their ring slot (distance 8) is re-read.
                if (CACHED && isLeader && (i & 3) == 0)
                    __builtin_amdgcn_fence(__ATOMIC_ACQUIRE, "agent");
            }
        }
        // ---- shadow work while flags propagate / peers finish ----
        if (active) {
            if (LAYER == 1) out[(size_t)t * S_ELEMS + myb * HH + col] = h;
            if (t == TT - 1) {
                float* fin = out + Y_ELEMS + (LAYER == 0 ? 0 : 2) * S_ELEMS;
                fin[myb * HH + col] = h;
                fin[S_ELEMS + myb * HH + col] = c;
            }
        }
        if (LAYER == 0 && i + 1 < TT) {      // prefetch x[t+1] into registers
            const float* xp = x + ((size_t)(i + 1) * BB + b0 + r16) * CC + q8;
            #pragma unroll
            for (int kt = 0; kt < 8; ++kt) {
                xf0[kt] = *(const float4*)(xp + kt * 32);
                xf1[kt] = *(const float4*)(xp + kt * 32 + 4);
            }
        }
        // ---- barrier completion: aggregator (block 0) or gen-poll (others) ----
        if (i < TT) {
            const u32 tgt = (u32)(i + 1);
            if (blockIdx.x == 0) {
                if (tid < 64) {  // wave 0 scans all 256 slots, 4 per lane
                    const u32* p0 = slots + ((u32)tid * 4 + 0) * 32;
                    const u32* p1 = slots + ((u32)tid * 4 + 1) * 32;
                    const u32* p2 = slots + ((u32)tid * 4 + 2) * 32;
                    const u32* p3 = slots + ((u32)tid * 4 + 3) * 32;
                    u32 m;
                    do {
                        u32 va = ld_u32_sc(p0);
                        u32 vb = ld_u32_sc(p1);
                        u32 vc = ld_u32_sc(p2);
                        u32 vd = ld_u32_sc(p3);
                        m = min(min(va, vb), min(vc, vd));
                    } while (m < tgt);
                }
                __syncthreads();
                if (tid == 0) {
                    #pragma unroll
                    for (int k2 = 0; k2 < 4; ++k2) st_u32_sc(gen + k2 * 32, tgt);
                }
            } else {
                if (tid == 0) {
                    const u32* gp = gen + ((u32)blockIdx.x & 3) * 32;
                    while (ld_u32_sc(gp) < tgt) { }
                }
                __syncthreads();
            }
        }
    }
}

template <bool CACHED>
__global__ __launch_bounds__(256) __attribute__((amdgpu_waves_per_eu(1, 1)))
void k_lstm(const float* __restrict__ x,
            const float* __restrict__ c00,
            const float* __restrict__ c01,
            float* __restrict__ out,
            unsigned char* __restrict__ ws, u32 rmask, u64 h1off) {
    const int bid = blockIdx.x;
    if (bid < 128) run_ticks<0, CACHED>(x, c00, out, ws, bid, rmask, h1off);
    else           run_ticks<1, CACHED>(x, c01, out, ws, bid - 128, rmask, h1off);
}

extern "C" void kernel_launch(void* const* d_in, const int* in_sizes, int n_in,
                              void* d_out, int out_size, void* d_ws, size_t ws_size,
                              hipStream_t stream) {
    const float* x    = (const float*)d_in[0];
    const float* h0_0 = (const float*)d_in[1];
    const float* c0_0 = (const float*)d_in[2];
    const float* h0_1 = (const float*)d_in[3];
    const float* c0_1 = (const float*)d_in[4];
    const float* Wih0 = (const float*)d_in[5];
    const float* Whh0 = (const float*)d_in[6];
    const float* bih0 = (const float*)d_in[7];
    const float* bhh0 = (const float*)d_in[8];
    const float* Wih1 = (const float*)d_in[9];
    const float* Whh1 = (const float*)d_in[10];
    const float* bih1 = (const float*)d_in[11];
    const float* bhh1 = (const float*)d_in[12];
    float* out = (float*)d_out;
    unsigned char* ws = (unsigned char*)d_ws;

    // cached-L2 mode needs an 8-deep ring per layer
    const u64 NEED8 = (u64)WS_H0 + 16ull * H_SLOT_BYTES;  // 8,441,856
    const bool big = (u64)ws_size >= NEED8;
    const u32 rmask = big ? 7u : 1u;
    const u64 h1off = (u64)WS_H0 + (u64)(rmask + 1u) * H_SLOT_BYTES;

    k_init<<<128, 256, 0, stream>>>(bih0, bhh0, bih1, bhh1, h0_0, h0_1, ws, h1off);
    k_wprep<<<1792, 256, 0, stream>>>(Wih0, Whh0, Wih1, Whh1, ws);
    if (big) k_lstm<true><<<256, 256, 0, stream>>>(x, c0_0, c0_1, out, ws, rmask, h1off);
    else     k_lstm<false><<<256, 256, 0, stream>>>(x, c0_0, c0_1, out, ws, rmask, h1off);
}